// Round 3
// baseline (403.555 us; speedup 1.0000x reference)
//
#include <hip/hip_runtime.h>
#include <math.h>

// sources: [4][32][512][512] fp32, kernels: [12][3][3] fp32, out: same as sources
// out_i = s_i - sum_j [ conv(s_j, kc_ij) + conv((s_j^0.5 * s_i)^(2/3), ki_ij) ]
//
// Key identity: with a = v^(1/3):  s = a^3,  (s_j^0.5 * s_i)^(2/3) = a_j * a_i^2.
// => stage ONLY a in LDS (~21.8 KB -> 7 blocks/CU), no per-pair exp2; raw
//    values reconstructed as a^3 (2 mults).
// Edge sweep (0,1),(1,2),(2,3): each edge computes both directed pairs from one
// pair of row-windows; each channel's output stored from registers when done.
//
// LAUNCH BOUNDS HISTORY (do not regress):
//   (256,8): 64-VGPR cap -> massive spill, 1.2 GB HBM writes, 518 us.
//   (256,4): allocator pinned to 64 VGPR, ~18 dw/thread spill (WRITE 278 MB),
//            AND occupancy stuck at 44% (16 waves/CU) -> 244 us. The second
//            arg acts as a waves/EU cap on this toolchain.
//   (256):   no constraint -> natural ~80-100 VGPR live set, no spill,
//            occupancy limited by LDS/VGPR only.

#define NCH  4
#define NIMG 32
#define HH   512
#define WW   512

#define TW   64
#define TH   16
#define HTWU 66            // used halo width
#define HTW  68            // padded stride (272 B, 16B-aligned rows)
#define HTH  18            // rows read by the conv
#define HTHS 20            // staged rows (padded so staging is branch-free)

#if __has_builtin(__builtin_amdgcn_exp2f)
#define EXP2(x) __builtin_amdgcn_exp2f(x)
#else
#define EXP2(x) exp2f(x)
#endif
#if __has_builtin(__builtin_amdgcn_logf)
#define LOG2(x) __builtin_amdgcn_logf(x)
#else
#define LOG2(x) __log2f(x)
#endif

__device__ __forceinline__ void load_row6(const float* __restrict__ row, float w[6]) {
    const float4 a = *(const float4*)row;          // ds_read_b128 (16B aligned)
    const float2 b = *(const float2*)(row + 4);    // ds_read_b64
    w[0] = a.x; w[1] = a.y; w[2] = a.z; w[3] = a.w; w[4] = b.x; w[5] = b.y;
}

// Edge between channels x and y = x+1 (a-values in Sx, Sy).
//   accX += conv(a_y^3, ker[KCX]) + conv(a_x^2 * a_y, ker[KIX])   (i=x, j=y)
//   accY += conv(a_x^3, ker[KCY]) + conv(a_y^2 * a_x, ker[KIY])   (i=y, j=x)
// cx receives the center-row a of channel x (cols tx4+1..tx4+4); cy only when
// CAPY (last edge) -- channel y's center is otherwise reloaded as ax of the
// next edge, so capturing it would just burn 4 registers.
template<int KCX, int KIX, int KCY, int KIY, bool CAPY>
__device__ __forceinline__ void edge_conv(
    const float (*Sx)[HTW], const float (*Sy)[HTW],
    int ty, int tx4, const float* __restrict__ ker,
    float accX[4], float accY[4], float cx[4], float cy[4])
{
    #pragma unroll
    for (int r = 0; r < 3; ++r) {
        float ax[6], ay[6];
        load_row6(&Sx[ty + r][tx4], ax);
        load_row6(&Sy[ty + r][tx4], ay);
        if (r == 1) {
            #pragma unroll
            for (int q = 0; q < 4; ++q) cx[q] = ax[q + 1];
            if (CAPY) {
                #pragma unroll
                for (int q = 0; q < 4; ++q) cy[q] = ay[q + 1];
            }
        }
        float ay2[6];
        #pragma unroll
        for (int q = 0; q < 6; ++q) ay2[q] = ay[q] * ay[q];

        // direction i=x (neighbor j=y): raw_y = ay^3, inter = ax^2 * ay
        {
            float w[6], t[6];
            #pragma unroll
            for (int q = 0; q < 6; ++q) {
                w[q] = ay2[q] * ay[q];
                t[q] = (ax[q] * ax[q]) * ay[q];
            }
            #pragma unroll
            for (int q = 0; q < 4; ++q) {
                float s = accX[q];
                #pragma unroll
                for (int dx = 0; dx < 3; ++dx) {
                    s = fmaf(w[q + dx], ker[KCX * 9 + r * 3 + dx], s);
                    s = fmaf(t[q + dx], ker[KIX * 9 + r * 3 + dx], s);
                }
                accX[q] = s;
            }
        }
        // direction i=y (neighbor j=x): raw_x = ax^3, inter = ay^2 * ax
        {
            float w[6], t[6];
            #pragma unroll
            for (int q = 0; q < 6; ++q) {
                w[q] = (ax[q] * ax[q]) * ax[q];
                t[q] = ay2[q] * ax[q];
            }
            #pragma unroll
            for (int q = 0; q < 4; ++q) {
                float s = accY[q];
                #pragma unroll
                for (int dx = 0; dx < 3; ++dx) {
                    s = fmaf(w[q + dx], ker[KCY * 9 + r * 3 + dx], s);
                    s = fmaf(t[q + dx], ker[KIY * 9 + r * 3 + dx], s);
                }
                accY[q] = s;
            }
        }
    }
}

// out = center^3 - bleed, dwordx4 store
__device__ __forceinline__ void store_out(float* __restrict__ p,
                                          const float c[4], const float a[4]) {
    float4 o;
    o.x = c[0] * c[0] * c[0] - a[0];
    o.y = c[1] * c[1] * c[1] - a[1];
    o.z = c[2] * c[2] * c[2] - a[2];
    o.w = c[3] * c[3] * c[3] - a[3];
    *(float4*)p = o;
}

__global__ __launch_bounds__(256) void bleed_kernel(
    const float* __restrict__ src,   // [4][32][512][512]
    const float* __restrict__ ker,   // [12][3][3]
    float* __restrict__ out)
{
    __shared__ __align__(16) float sA[NCH][HTHS][HTW];  // a = v^(1/3)

    const int tid    = threadIdx.x;
    const int tx     = tid & 15;      // col group: cols 4*tx .. 4*tx+3
    const int ty     = tid >> 4;      // row 0..15
    const int tx4    = tx * 4;
    const int tile_x = blockIdx.x * TW;
    const int tile_y = blockIdx.y * TH;
    const int n      = blockIdx.z;    // image index

    const size_t plane = (size_t)HH * WW;

    // ---- stage a = v^(1/3) for all 4 channels, zero-padded halo ----
    // 64-lane rows: lane lx covers col lx; lanes 0,1 also cover cols 64,65.
    // Branch-free over 20 rows (rows 18,19 are padding, never read) so the
    // 5 global loads per channel can batch and overlap their latency.
    {
        const int lx = tid & 63;
        const int ry = tid >> 6;      // wave-uniform row phase 0..3
        #pragma unroll
        for (int c = 0; c < NCH; ++c) {
            const float* sp = src + ((size_t)c * NIMG + n) * plane;
            #pragma unroll
            for (int it = 0; it < 5; ++it) {
                const int ly = ry + it * 4;        // 0..19, always in-bounds
                const int gy = tile_y - 1 + ly;
                const bool yok = (unsigned)gy < HH;
                const float* rp = sp + (size_t)gy * WW;
                const int gx = tile_x - 1 + lx;
                float v = 0.0f;
                if (yok && (unsigned)gx < WW) v = rp[gx];
                sA[c][ly][lx] = EXP2(0.33333334f * LOG2(v));   // v=0 -> a=0
                if (lx < 2) {
                    const int gx2 = gx + 64;
                    float v2 = 0.0f;
                    if (yok && (unsigned)gx2 < WW) v2 = rp[gx2];
                    sA[c][ly][64 + lx] = EXP2(0.33333334f * LOG2(v2));
                }
            }
        }
    }
    __syncthreads();   // only barrier; everything after is read-only LDS

    const int gy  = tile_y + ty;
    const int gx0 = tile_x + tx4;
    float* outp = out + (size_t)n * plane + (size_t)gy * WW + gx0;
    const size_t cstride = (size_t)NIMG * plane;

    float accL[4] = {0.f, 0.f, 0.f, 0.f};
    float accH[4] = {0.f, 0.f, 0.f, 0.f};
    float cA[4], cB[4];

    // edge (0,1): i=0 gets kc=0,ki=1 ; i=1 gets kc=2,ki=3
    edge_conv<0, 1, 2, 3, false>(sA[0], sA[1], ty, tx4, ker, accL, accH, cA, cB);
    store_out(outp, cA, accL);                       // channel 0 complete

    #pragma unroll
    for (int q = 0; q < 4; ++q) { accL[q] = accH[q]; accH[q] = 0.f; }

    // edge (1,2): i=1 gets kc=4,ki=5 ; i=2 gets kc=6,ki=7
    edge_conv<4, 5, 6, 7, false>(sA[1], sA[2], ty, tx4, ker, accL, accH, cA, cB);
    store_out(outp + cstride, cA, accL);             // channel 1 complete

    #pragma unroll
    for (int q = 0; q < 4; ++q) { accL[q] = accH[q]; accH[q] = 0.f; }

    // edge (2,3): i=2 gets kc=8,ki=9 ; i=3 gets kc=10,ki=11
    edge_conv<8, 9, 10, 11, true>(sA[2], sA[3], ty, tx4, ker, accL, accH, cA, cB);
    store_out(outp + 2 * cstride, cA, accL);         // channel 2 complete
    store_out(outp + 3 * cstride, cB, accH);         // channel 3 complete
}

extern "C" void kernel_launch(void* const* d_in, const int* in_sizes, int n_in,
                              void* d_out, int out_size, void* d_ws, size_t ws_size,
                              hipStream_t stream) {
    const float* src = (const float*)d_in[0];
    const float* ker = (const float*)d_in[1];
    float* out = (float*)d_out;

    dim3 grid(WW / TW, HH / TH, NIMG);   // (8, 32, 32) = 8192 blocks
    dim3 block(256);
    bleed_kernel<<<grid, block, 0, stream>>>(src, ker, out);
}

// Round 4
// 238.560 us; speedup vs baseline: 1.6916x; 1.6916x over previous
//
#include <hip/hip_runtime.h>
#include <math.h>

// sources: [4][32][512][512] fp32, kernels: [12][3][3] fp32, out: same as sources
// out_i = s_i - sum_j [ conv(s_j, kc_ij) + conv((s_j^0.5 * s_i)^(2/3), ki_ij) ]
//
// Identity: a = v^(1/3) => s = a^3, (s_j^0.5 * s_i)^(2/3) = a_j * a_i^2.
// Stage only a in LDS; conv is multiply/FMA only; edge sweep (0,1),(1,2),(2,3).
//
// ROUND-4 CHANGE (Little's-law fix): staging was scalar 4 B/lane loads ->
// read BW = bytes_in_flight/latency capped the whole kernel (~250 us, 75%
// stall, VALUBusy 18%). Now: float4 staging loads, all 5 per thread issued
// before any use. LDS col k = global col (tile_x + k - 4), stride 72:
// global float4 loads AND LDS b128 writes both 16B-aligned; halos at cols
// 3 and 68 via 2 predicated scalar loads. Conv window = LDS cols
// tx4+3..tx4+8 (same VALUES as before: aligned b128 + 2 b32 / ds_read2).
//
// LAUNCH BOUNDS HISTORY (do not regress): (256,8) -> 64-VGPR spill disaster;
// (256,4) -> 64-VGPR pin + spills. Leave unbounded.

#define NCH  4
#define NIMG 32
#define HH   512
#define WW   512

#define TW   64
#define TH   16
#define HTW  72            // LDS row stride (dwords); col k = global tile_x+k-4
#define HTH  18
#define NTASK (NCH * HTH)  // 72 row-channel staging tasks

#if __has_builtin(__builtin_amdgcn_exp2f)
#define EXP2(x) __builtin_amdgcn_exp2f(x)
#else
#define EXP2(x) exp2f(x)
#endif
#if __has_builtin(__builtin_amdgcn_logf)
#define LOG2(x) __builtin_amdgcn_logf(x)
#else
#define LOG2(x) __log2f(x)
#endif

__device__ __forceinline__ float cbrtfast(float v) {
    return EXP2(0.33333334f * LOG2(v));   // v=0 -> -inf -> 0 (correct zero-pad)
}

// Window = LDS cols tx4+3 .. tx4+8 (global cols tile_x+tx4-1 .. +4).
// row points at &S[y][tx4]: aligned b128 at +4 covers w[1..4]; w[0],w[5]
// are two b32s at +3/+8 (ds_read2_b32 candidates).
__device__ __forceinline__ void load_row6(const float* __restrict__ row, float w[6]) {
    const float4 m = *(const float4*)(row + 4);
    w[0] = row[3];
    w[1] = m.x; w[2] = m.y; w[3] = m.z; w[4] = m.w;
    w[5] = row[8];
}

// Edge between channels x and y = x+1 (a-values in Sx, Sy).
//   accX += conv(a_y^3, ker[KCX]) + conv(a_x^2 * a_y, ker[KIX])   (i=x, j=y)
//   accY += conv(a_x^3, ker[KCY]) + conv(a_y^2 * a_x, ker[KIY])   (i=y, j=x)
template<int KCX, int KIX, int KCY, int KIY, bool CAPY>
__device__ __forceinline__ void edge_conv(
    const float (*Sx)[HTW], const float (*Sy)[HTW],
    int ty, int tx4, const float* __restrict__ ker,
    float accX[4], float accY[4], float cx[4], float cy[4])
{
    #pragma unroll
    for (int r = 0; r < 3; ++r) {
        float ax[6], ay[6];
        load_row6(&Sx[ty + r][tx4], ax);
        load_row6(&Sy[ty + r][tx4], ay);
        if (r == 1) {
            #pragma unroll
            for (int q = 0; q < 4; ++q) cx[q] = ax[q + 1];
            if (CAPY) {
                #pragma unroll
                for (int q = 0; q < 4; ++q) cy[q] = ay[q + 1];
            }
        }
        float ay2[6];
        #pragma unroll
        for (int q = 0; q < 6; ++q) ay2[q] = ay[q] * ay[q];

        // i=x (neighbor j=y): raw_y = ay^3, inter = ax^2 * ay
        {
            float w[6], t[6];
            #pragma unroll
            for (int q = 0; q < 6; ++q) {
                w[q] = ay2[q] * ay[q];
                t[q] = (ax[q] * ax[q]) * ay[q];
            }
            #pragma unroll
            for (int q = 0; q < 4; ++q) {
                float s = accX[q];
                #pragma unroll
                for (int dx = 0; dx < 3; ++dx) {
                    s = fmaf(w[q + dx], ker[KCX * 9 + r * 3 + dx], s);
                    s = fmaf(t[q + dx], ker[KIX * 9 + r * 3 + dx], s);
                }
                accX[q] = s;
            }
        }
        // i=y (neighbor j=x): raw_x = ax^3, inter = ay^2 * ax
        {
            float w[6], t[6];
            #pragma unroll
            for (int q = 0; q < 6; ++q) {
                w[q] = (ax[q] * ax[q]) * ax[q];
                t[q] = ay2[q] * ax[q];
            }
            #pragma unroll
            for (int q = 0; q < 4; ++q) {
                float s = accY[q];
                #pragma unroll
                for (int dx = 0; dx < 3; ++dx) {
                    s = fmaf(w[q + dx], ker[KCY * 9 + r * 3 + dx], s);
                    s = fmaf(t[q + dx], ker[KIY * 9 + r * 3 + dx], s);
                }
                accY[q] = s;
            }
        }
    }
}

__device__ __forceinline__ void store_out(float* __restrict__ p,
                                          const float c[4], const float a[4]) {
    float4 o;
    o.x = c[0] * c[0] * c[0] - a[0];
    o.y = c[1] * c[1] * c[1] - a[1];
    o.z = c[2] * c[2] * c[2] - a[2];
    o.w = c[3] * c[3] * c[3] - a[3];
    *(float4*)p = o;
}

__global__ __launch_bounds__(256) void bleed_kernel(
    const float* __restrict__ src,   // [4][32][512][512]
    const float* __restrict__ ker,   // [12][3][3]
    float* __restrict__ out)
{
    __shared__ __align__(16) float sA[NCH][HTH][HTW];  // a = v^(1/3)

    const int tid    = threadIdx.x;
    const int tx     = tid & 15;      // col group: cols 4*tx .. 4*tx+3
    const int ty     = tid >> 4;      // row 0..15
    const int tx4    = tx * 4;
    const int tile_x = blockIdx.x * TW;
    const int tile_y = blockIdx.y * TH;
    const int n      = blockIdx.z;    // image index

    const size_t plane = (size_t)HH * WW;

    // ---- stage a = v^(1/3), zero-padded halo; float4 loads, batched ----
    // 16 groups of 16 lanes; task t = (channel c = t/18, row = t%18).
    // Lane L loads float4 of global cols tile_x+4L..+3 -> LDS cols 4+4L..7+4L.
    // Lane 0 loads left halo (col tile_x-1 -> LDS col 3), lane 1 right halo
    // (col tile_x+64 -> LDS col 68). All 5 tasks' loads issued before use.
    {
        const int g = tid >> 4;
        const int L = tid & 15;
        float4 vv[5];
        float  hv[5];
        #pragma unroll
        for (int it = 0; it < 5; ++it) {
            const int t   = g + it * 16;
            const int c   = t / HTH;
            const int row = t - c * HTH;
            const int gy  = tile_y - 1 + row;
            float4 v = make_float4(0.f, 0.f, 0.f, 0.f);
            float  h = 0.f;
            if (t < NTASK && (unsigned)gy < HH) {
                const float* rp = src + ((size_t)c * NIMG + n) * plane
                                      + (size_t)gy * WW;
                v = *(const float4*)(rp + tile_x + 4 * L);
                if (L == 0 && tile_x > 0)       h = rp[tile_x - 1];
                if (L == 1 && tile_x + TW < WW) h = rp[tile_x + TW];
            }
            vv[it] = v;
            hv[it] = h;
        }
        #pragma unroll
        for (int it = 0; it < 5; ++it) {
            const int t   = g + it * 16;
            if (t < NTASK) {
                const int c   = t / HTH;
                const int row = t - c * HTH;
                float4 a;
                a.x = cbrtfast(vv[it].x);
                a.y = cbrtfast(vv[it].y);
                a.z = cbrtfast(vv[it].z);
                a.w = cbrtfast(vv[it].w);
                const float ah = cbrtfast(hv[it]);
                *(float4*)&sA[c][row][4 + 4 * L] = a;    // 16B-aligned ds_write
                if (L == 0) sA[c][row][3]  = ah;
                if (L == 1) sA[c][row][68] = ah;
            }
        }
    }
    __syncthreads();   // only barrier; everything after is read-only LDS

    const int gy  = tile_y + ty;
    const int gx0 = tile_x + tx4;
    float* outp = out + (size_t)n * plane + (size_t)gy * WW + gx0;
    const size_t cstride = (size_t)NIMG * plane;

    float accL[4] = {0.f, 0.f, 0.f, 0.f};
    float accH[4] = {0.f, 0.f, 0.f, 0.f};
    float cA[4], cB[4];

    // edge (0,1): i=0 gets kc=0,ki=1 ; i=1 gets kc=2,ki=3
    edge_conv<0, 1, 2, 3, false>(sA[0], sA[1], ty, tx4, ker, accL, accH, cA, cB);
    store_out(outp, cA, accL);                       // channel 0 complete

    #pragma unroll
    for (int q = 0; q < 4; ++q) { accL[q] = accH[q]; accH[q] = 0.f; }

    // edge (1,2): i=1 gets kc=4,ki=5 ; i=2 gets kc=6,ki=7
    edge_conv<4, 5, 6, 7, false>(sA[1], sA[2], ty, tx4, ker, accL, accH, cA, cB);
    store_out(outp + cstride, cA, accL);             // channel 1 complete

    #pragma unroll
    for (int q = 0; q < 4; ++q) { accL[q] = accH[q]; accH[q] = 0.f; }

    // edge (2,3): i=2 gets kc=8,ki=9 ; i=3 gets kc=10,ki=11
    edge_conv<8, 9, 10, 11, true>(sA[2], sA[3], ty, tx4, ker, accL, accH, cA, cB);
    store_out(outp + 2 * cstride, cA, accL);         // channel 2 complete
    store_out(outp + 3 * cstride, cB, accH);         // channel 3 complete
}

extern "C" void kernel_launch(void* const* d_in, const int* in_sizes, int n_in,
                              void* d_out, int out_size, void* d_ws, size_t ws_size,
                              hipStream_t stream) {
    const float* src = (const float*)d_in[0];
    const float* ker = (const float*)d_in[1];
    float* out = (float*)d_out;

    dim3 grid(WW / TW, HH / TH, NIMG);   // (8, 32, 32) = 8192 blocks
    dim3 block(256);
    bleed_kernel<<<grid, block, 0, stream>>>(src, ker, out);
}